// Round 18
// baseline (1075.469 us; speedup 1.0000x reference)
//
#include <hip/hip_runtime.h>

typedef __attribute__((ext_vector_type(8))) short bf16x8;
typedef __attribute__((ext_vector_type(4))) float f32x4;

__device__ __forceinline__ unsigned short f2bf(float x) {
    unsigned u = __float_as_uint(x);
    u += 0x7FFFu + ((u >> 16) & 1u);
    return (unsigned short)(u >> 16);
}
__device__ __forceinline__ float sigm(float x) { return 1.0f / (1.0f + __expf(-x)); }
__device__ __forceinline__ float ftanh(float x) {
    float e = __expf(2.f * x);
    return 1.f - 2.f / (e + 1.f);
}

// async global->LDS, 16B/lane; global addr is PER-LANE, LDS dest = base + lane*16
__device__ __forceinline__ void gld16(const unsigned short* g, unsigned short* l) {
    __builtin_amdgcn_global_load_lds((const __attribute__((address_space(1))) void*)g,
                                     (__attribute__((address_space(3))) void*)l, 16, 0, 0);
}

// ---- flag primitives ----
__device__ __forceinline__ void st_plain32(unsigned* p, unsigned v) {  // -> XCD L2
    asm volatile("global_store_dword %0, %1, off" :: "v"(p), "v"(v) : "memory");
}
__device__ __forceinline__ void st_wt32(unsigned* p, unsigned v) {     // -> MALL
    asm volatile("global_store_dword %0, %1, off sc0 sc1" :: "v"(p), "v"(v) : "memory");
}
__device__ __forceinline__ unsigned ld_mall(const unsigned* p) {       // read MALL (per-lane addr)
    unsigned v;
    asm volatile("global_load_dword %0, %1, off sc0 sc1\n\ts_waitcnt vmcnt(0)"
                 : "=v"(v) : "v"(p) : "memory");
    return v;
}
__device__ __forceinline__ void st_wt16(unsigned short* p, unsigned v) {
    asm volatile("global_store_short %0, %1, off sc0 sc1" :: "v"(p), "v"(v) : "memory");
}

// DPP quad-lane exchanges (1-cycle VALU)
__device__ __forceinline__ float dppx1(float x) {
    return __int_as_float(__builtin_amdgcn_mov_dpp(__float_as_int(x), 0xB1, 0xF, 0xF, true));
}
__device__ __forceinline__ float dppx2(float x) {
    return __int_as_float(__builtin_amdgcn_mov_dpp(__float_as_int(x), 0x4E, 0xF, 0xF, true));
}

// ---------------- packing kernels (round-6-verified) ----------------
__global__ __launch_bounds__(256) void k_conv_x(const float* __restrict__ x,
                                                unsigned short* __restrict__ Xp) {
    int i = blockIdx.x * 256 + threadIdx.x;
    int rb = i >> 10, kc = (i >> 6) & 15, ln = i & 63;
    int row = (rb << 4) + (ln & 15);
    int k   = (kc << 5) + ((ln >> 4) << 3);
    const float* s = x + (size_t)row * 512 + k;
    float4 v0 = *(const float4*)s, v1 = *(const float4*)(s + 4);
    unsigned short o[8] = {f2bf(v0.x), f2bf(v0.y), f2bf(v0.z), f2bf(v0.w),
                           f2bf(v1.x), f2bf(v1.y), f2bf(v1.z), f2bf(v1.w)};
    *(bf16x8*)(Xp + (size_t)i * 8) = *(bf16x8*)o;
}

__global__ __launch_bounds__(256) void k_conv_w(const float* __restrict__ Wih,
                                                const float* __restrict__ Whh,
                                                unsigned short* __restrict__ Wp) {
    int i = blockIdx.x * 256 + threadIdx.x;
    int wrb = i >> 11, kc = (i >> 6) & 31, ln = i & 63;
    int j = (wrb << 4) + (ln & 15);
    int k = (kc << 5) + ((ln >> 4) << 3);
    int srow = (j & 3) * 512 + (j >> 2);              // torch row g*512+hc
    const float* s = (k < 512) ? (Wih + (size_t)srow * 512 + k)
                               : (Whh + (size_t)srow * 512 + (k - 512));
    float4 v0 = *(const float4*)s, v1 = *(const float4*)(s + 4);
    unsigned short o[8] = {f2bf(v0.x), f2bf(v0.y), f2bf(v0.z), f2bf(v0.w),
                           f2bf(v1.x), f2bf(v1.y), f2bf(v1.z), f2bf(v1.w)};
    *(bf16x8*)(Wp + (size_t)i * 8) = *(bf16x8*)o;
}

struct DP {
    const unsigned short* Xp;
    unsigned short *Hp0, *Hp1, *Hp2;
    unsigned short *Xq1, *Xq2;
    const unsigned short *Wp0, *Wp1, *Wp2;
    const float *bi0, *bh0, *bi1, *bh1, *bi2, *bh2;
    float* Out;
    unsigned int* flags;   // [0,8192) iflag lines, [8192,16384) mflag lines
                           // line (cid*32+w)*32 dwords; dwords 0..3 = per-WAVE flags
};

__device__ __forceinline__ void quadT(f32x4 a, int sq, float& G0, float& G1, float& G2, float& G3) {
    float a0 = a[0], a1 = a[1], a2 = a[2], a3 = a[3];
    float p1 = (sq & 1) ? a0 : a1; float g1_ = dppx1(p1);
    float p2 = (sq & 1) ? a2 : a3; float g2_ = dppx1(p2);
    float m0 = (sq & 1) ? g1_ : a0, m1 = (sq & 1) ? a1 : g1_;
    float m2 = (sq & 1) ? g2_ : a2, m3 = (sq & 1) ? a3 : g2_;
    float q1 = (sq & 2) ? m0 : m2; float h1_ = dppx2(q1);
    float q2 = (sq & 2) ? m1 : m3; float h2_ = dppx2(q2);
    G0 = (sq & 2) ? h1_ : m0; G1 = (sq & 2) ? h2_ : m1;
    G2 = (sq & 2) ? m2 : h1_; G3 = (sq & 2) ? m3 : h2_;
}

#define PIN8(A,B,C,D,E,F,G,H) \
    asm volatile("" : "+v"(A),"+v"(B),"+v"(C),"+v"(D),"+v"(E),"+v"(F),"+v"(G),"+v"(H))
#define SBAR()  __builtin_amdgcn_sched_barrier(0)
#define MEMBAR() asm volatile("" ::: "memory")
#define RAWBAR() do { MEMBAR(); SBAR(); __builtin_amdgcn_s_barrier(); SBAR(); MEMBAR(); } while (0)
#define VMC(n) asm volatile("s_waitcnt vmcnt(" #n ")" ::: "memory")

// Persistent dilated-LSTM, grid 256, XCD-clustered (cid = bid&7, w = bid>>3).
// r18 KEY CHANGE: PER-WAVE flags (4 dwords in each wg's 128B line). A wave
// publishes IMMEDIATELY after its own counted VMC acks its own h-slice --
// no wait for the slowest wave, and B2 is DELETED (l==0: 3 barriers/step).
// Consumer poll: lane w gld16s wg w's 16B quad -> checks all 4 with the
// exact-match window (v-t)<=1 (stale prior-replay value T rejected for
// t<T-1; t==T-1 and escalation use per-lane spread ld_mall on the MALL
// mirror). Cross-layer semantics unchanged: flag >= s+2 => wt16 <= s
// drained, now justified PER-WAVE by each wave's own B1-path VMC(0).
// Queue algebra per path (issue-order, newest-last):
//  l0 !alias: [Hd2,gx8,wt2] VMC(10) -> pub2 -> [gx8,wt2,pub2] VMC(4) -> B3
//  l0  alias: [wt2,gx8] VMC(8) -> pub2 -> [gx8,pub2] VMC(2) -> B3
//  l1 !alias: VMC(0) pre-gate; [gx16,wt4] -> pub2 -> VMC(6) -> B3
//  l2:        VMC(0) pre-gate; [gx16] -> pub2 -> VMC(2) -> B3
__global__ __launch_bounds__(256, 1) void k_drnn(DP p) {
    const int tid = threadIdx.x, lane = tid & 63, wv = tid >> 6;
    const int l15 = lane & 15, lhi = lane >> 4, sq = l15 & 3;

    const int b = blockIdx.x;
    const int cid = b & 7, w = b >> 3;
    int l, c, T, P, N;
    if (cid < 2)      { l = 0; c = cid;     T = 256; P = 1; N = 64;  }
    else if (cid < 4) { l = 1; c = cid - 2; T = 128; P = 2; N = 128; }
    else              { l = 2; c = cid - 4; T = 64;  P = 2; N = 256; }

    const unsigned short* Xs = (l == 0) ? p.Xp  : (l == 1 ? p.Xq1 : p.Xq2);
    unsigned short*       Hd = (l == 0) ? p.Hp0 : (l == 1 ? p.Hp1 : p.Hp2);
    unsigned short*       Xw = (l == 0) ? p.Xq1 : (l == 1 ? p.Xq2 : nullptr);
    const unsigned short* Ws = (l == 0) ? p.Wp0 : (l == 1 ? p.Wp1 : p.Wp2);
    const float* bi = (l == 0) ? p.bi0 : (l == 1 ? p.bi1 : p.bi2);
    const float* bh = (l == 0) ? p.bh0 : (l == 1 ? p.bh1 : p.bh2);
    const int R0 = c * (P * 32);
    const int alias = (p.Xq1 == p.Hp0);

    __shared__ unsigned short At[65536];   // 128 KiB
    __shared__ unsigned pollbuf[256];      // 1KB poll scratch (64 lanes x 16B)

    const unsigned short* wbase = Ws + ((size_t)(((w << 2) + wv) * 32) << 9) + lane * 8;
#define DECLW(n) bf16x8 w##n = *(const bf16x8*)(wbase + (n << 9));
    DECLW(0) DECLW(1) DECLW(2) DECLW(3) DECLW(4) DECLW(5) DECLW(6) DECLW(7)
    DECLW(8) DECLW(9) DECLW(10) DECLW(11) DECLW(12) DECLW(13) DECLW(14) DECLW(15)
    DECLW(16) DECLW(17) DECLW(18) DECLW(19) DECLW(20) DECLW(21) DECLW(22) DECLW(23)
    DECLW(24) DECLW(25) DECLW(26) DECLW(27) DECLW(28) DECLW(29) DECLW(30) DECLW(31)

    const int hcol = (w << 4) + (wv << 2) + (l15 >> 2);
    const float bs0 = bi[hcol]        + bh[hcol];
    const float bs1 = bi[512 + hcol]  + bh[512 + hcol];
    const float bs2 = bi[1024 + hcol] + bh[1024 + hcol];
    const float bs3 = bi[1536 + hcol] + bh[1536 + hcol];

    const int kch = hcol >> 5;
    const int lane16 = (((hcol & 31) >> 3) << 4) + ((lhi << 2) + sq);
    const int st_lt = lane16 * 8 + (hcol & 7);

    float cst0 = 0.f, cst1 = 0.f, cst2 = 0.f, cst3 = 0.f;
    unsigned int* iflagL = p.flags;
    unsigned int* mflagL = p.flags + 8192;
    unsigned int* myIf = iflagL + (((cid << 5) + w) << 5) + wv;   // per-wave slot
    unsigned int* myMf = mflagL + (((cid << 5) + w) << 5) + wv;
    int fastok = 1;

#define KPX(na, nb, E0, E1, O0, O1, A0, A1) { \
    bf16x8 xa = *(const bf16x8*)((A0) + ((na) << 9)); \
    bf16x8 xb = *(const bf16x8*)((A1) + ((na) << 9)); \
    bf16x8 ya = *(const bf16x8*)((A0) + ((nb) << 9)); \
    bf16x8 yb = *(const bf16x8*)((A1) + ((nb) << 9)); \
    E0 = __builtin_amdgcn_mfma_f32_16x16x32_bf16(xa, w##na, E0, 0, 0, 0); \
    E1 = __builtin_amdgcn_mfma_f32_16x16x32_bf16(xb, w##na, E1, 0, 0, 0); \
    O0 = __builtin_amdgcn_mfma_f32_16x16x32_bf16(ya, w##nb, O0, 0, 0, 0); \
    O1 = __builtin_amdgcn_mfma_f32_16x16x32_bf16(yb, w##nb, O1, 0, 0, 0); }

#define XH(E0, E1, O0, O1, A0, A1) \
    KPX(0,1,E0,E1,O0,O1,A0,A1) KPX(2,3,E0,E1,O0,O1,A0,A1) \
    KPX(4,5,E0,E1,O0,O1,A0,A1) KPX(6,7,E0,E1,O0,O1,A0,A1) \
    KPX(8,9,E0,E1,O0,O1,A0,A1) KPX(10,11,E0,E1,O0,O1,A0,A1) \
    KPX(12,13,E0,E1,O0,O1,A0,A1) KPX(14,15,E0,E1,O0,O1,A0,A1)
#define HH(E0, E1, O0, O1, A0, A1) \
    KPX(16,17,E0,E1,O0,O1,A0,A1) KPX(18,19,E0,E1,O0,O1,A0,A1) \
    KPX(20,21,E0,E1,O0,O1,A0,A1) KPX(22,23,E0,E1,O0,O1,A0,A1) \
    KPX(24,25,E0,E1,O0,O1,A0,A1) KPX(26,27,E0,E1,O0,O1,A0,A1) \
    KPX(28,29,E0,E1,O0,O1,A0,A1) KPX(30,31,E0,E1,O0,O1,A0,A1)

#define PWC(RV, CSTV, HV) { \
    float G0, G1, G2, G3; quadT(RV, sq, G0, G1, G2, G3); \
    float cn = sigm(G1 + bs1) * CSTV + sigm(G0 + bs0) * ftanh(G2 + bs2); \
    HV = sigm(G3 + bs3) * ftanh(cn); CSTV = cn; }

#define STAGE_X(TT) { \
    const int RxN = ((TT) * N + R0) >> 4; \
    for (int i = 0; i < P * 8; ++i) { \
        int q = wv * (P * 8) + i, rb = q >> 4, kc = q & 15; \
        gld16(Xs + ((size_t)((RxN + rb) * 16 + kc) << 9) + lane * 8, \
              &At[(rb * 32 + kc) << 9]); } }
#define STAGE_H(TT) { \
    const int RhN = ((TT) * N + R0) >> 4; \
    for (int i = 0; i < P * 8; ++i) { \
        int q = wv * (P * 8) + i, rb = q >> 4, kc = q & 15; \
        gld16(Hd + ((size_t)((RhN + rb) * 16 + kc) << 9) + lane * 8, \
              &At[(rb * 32 + 16 + kc) << 9]); } }

// cross-layer gate: per-lane spread ld_mall over producer's per-wave mflags
// (lane covers wg = lane>>1, wave-pair (lane&1)*2, +1)
#define MPOLL(TT) { \
    if (l == 1 && wv == 1) { \
        unsigned nd = (unsigned)(2 * (TT) + c + 2); if (nd > 256u) nd = 256u; \
        const unsigned* q0 = mflagL + ((0 + (lane >> 1)) << 5) + ((lane & 1) << 1); \
        const unsigned* q1 = mflagL + (((32 + (lane >> 1))) << 5) + ((lane & 1) << 1); \
        int n = 0; \
        for (;;) { \
            unsigned a = ld_mall(q0), bb = ld_mall(q0 + 1); \
            unsigned cc = ld_mall(q1), dd = ld_mall(q1 + 1); \
            if (__all(a >= nd && bb >= nd && cc >= nd && dd >= nd)) break; \
            if (++n > (1 << 22)) break; \
        } \
    } \
    if (l == 2 && wv == 1) { \
        unsigned nd = (unsigned)(2 * (TT) + (c >> 1) + 2); if (nd > 128u) nd = 128u; \
        const unsigned* q0 = mflagL + ((((2 + (c & 1)) << 5) + (lane >> 1)) << 5) + ((lane & 1) << 1); \
        int n = 0; \
        for (;;) { \
            unsigned a = ld_mall(q0), bb = ld_mall(q0 + 1); \
            if (__all(a >= nd && bb >= nd)) break; \
            if (++n > (1 << 22)) break; \
        } \
    } }

    f32x4 e0 = {0,0,0,0}, e1 = {0,0,0,0}, o0 = {0,0,0,0}, o1 = {0,0,0,0};
    f32x4 e2 = {0,0,0,0}, e3 = {0,0,0,0}, o2 = {0,0,0,0}, o3 = {0,0,0,0};
    const unsigned short* A00 = At + lane * 8;
    const unsigned short* A01 = A00 + (32 << 9);
    const unsigned short* A10 = A00 + (64 << 9);
    const unsigned short* A11 = A00 + (96 << 9);

    // ---------- prologue: x(0) staged + x-half partials ----------
    MPOLL(0);
    RAWBAR();
    STAGE_X(0);
    VMC(0);
    RAWBAR();
    { XH(e0, e1, o0, o1, A00, A01) }
    if (P == 2) { XH(e2, e3, o2, o3, A10, A11) }

    for (int t = 0; t < T; ++t) {
        PIN8(w0,w1,w2,w3,w4,w5,w6,w7);
        PIN8(w8,w9,w10,w11,w12,w13,w14,w15);
        PIN8(w16,w17,w18,w19,w20,w21,w22,w23);
        PIN8(w24,w25,w26,w27,w28,w29,w30,w31);

        const int RxB = (t * N + R0) >> 4;

        if (t > 0) {
            if (wv == 0) {
                const unsigned need = (unsigned)t;
                const unsigned* mp = mflagL + (((cid << 5) + (lane >> 1)) << 5) + ((lane & 1) << 1);
                if (t == T - 1 || !fastok) {         // authoritative MALL gate (spread)
                    int n = 0;
                    for (;;) {
                        unsigned a = ld_mall(mp), bb = ld_mall(mp + 1);
                        if (__all(a >= need && bb >= need)) break;
                        if (++n > (1 << 22)) break;
                    }
                } else {
                    const unsigned short* gip =
                        (const unsigned short*)(iflagL + (((cid << 5) + (lane & 31)) << 5));
                    volatile unsigned* pb = pollbuf;
                    int n = 0;
                    for (;;) {
                        gld16(gip, (unsigned short*)pollbuf);
                        VMC(0);
                        SBAR();
                        const int bse = (lane & 31) * 4;
                        unsigned v0 = pb[bse + 0] - need, v1 = pb[bse + 1] - need;
                        unsigned v2 = pb[bse + 2] - need, v3 = pb[bse + 3] - need;
                        if (__all(v0 <= 1u && v1 <= 1u && v2 <= 1u && v3 <= 1u)) break;
                        if (++n > 1024) {
                            fastok = 0;
                            int m = 0;
                            for (;;) {
                                unsigned a = ld_mall(mp), bb = ld_mall(mp + 1);
                                if (__all(a >= need && bb >= need)) break;
                                if (++m > (1 << 22)) break;
                            }
                            break;
                        }
                    }
                }
            }
            RAWBAR();                                 // B0: h(t-1) ready
            STAGE_H(t - 1);
            VMC(0);                                   // old wt/pubs long-retired: ~free
            RAWBAR();                                 // B1: h staged
            { HH(e0, e1, o0, o1, A00, A01) }
            if (P == 2) { HH(e2, e3, o2, o3, A10, A11) }
        }

        // ---- pointwise
        float hv0, hv1, hv2 = 0.f, hv3 = 0.f;
        { f32x4 r0 = e0 + o0, r1 = e1 + o1;
          PWC(r0, cst0, hv0) PWC(r1, cst1, hv1) }
        if (P == 2) {
          f32x4 r2 = e2 + o2, r3 = e3 + o3;
          PWC(r2, cst2, hv2) PWC(r3, cst3, hv3) }

        const unsigned short hb0 = f2bf(hv0), hb1 = f2bf(hv1);
        const unsigned short hb2 = f2bf(hv2), hb3 = f2bf(hv3);
        const size_t i0 = ((size_t)((RxB + 0) * 16 + kch) << 9) + st_lt;
        const size_t i1 = ((size_t)((RxB + 1) * 16 + kch) << 9) + st_lt;
        const size_t i2 = ((size_t)((RxB + 2) * 16 + kch) << 9) + st_lt;
        const size_t i3 = ((size_t)((RxB + 3) * 16 + kch) << 9) + st_lt;

        // ---- release stores (plain; MALL wt16 deferred to the shadow)
        if (!alias || l == 2) {
            Hd[i0] = hb0; Hd[i1] = hb1;
            if (P == 2) { Hd[i2] = hb2; Hd[i3] = hb3; }
        }
        if (alias && l < 2) {
            st_wt16(Xw + i0, hb0); st_wt16(Xw + i1, hb1);
            if (P == 2) { st_wt16(Xw + i2, hb2); st_wt16(Xw + i3, hb3); }
        }
        if (l == 2) {
            p.Out[((size_t)(((RxB + 0) << 4) + (lhi << 2) + sq)) * 512 + hcol] = hv0;
            p.Out[((size_t)(((RxB + 1) << 4) + (lhi << 2) + sq)) * 512 + hcol] = hv1;
            p.Out[((size_t)(((RxB + 2) << 4) + (lhi << 2) + sq)) * 512 + hcol] = hv2;
            p.Out[((size_t)(((RxB + 3) << 4) + (lhi << 2) + sq)) * 512 + hcol] = hv3;
        }
        MEMBAR(); SBAR();

        if (t + 1 < T) {
            if (l == 0) {
                if (t == 0) RAWBAR();                 // guard: prologue-XH vs x overwrite
                STAGE_X(t + 1);                       // 8 gld16
                if (!alias) { st_wt16(Xw + i0, hb0); st_wt16(Xw + i1, hb1); }
                MEMBAR(); SBAR();
                if (!alias) VMC(10); else VMC(8);     // own h acked
                // per-wave publish: each wave's lane0, immediately (no B2)
                if (lane == 0) {
                    st_plain32(myIf, (unsigned)(t + 1));
                    st_wt32(myMf, (unsigned)(t + 1));
                }
                MEMBAR(); SBAR();
                if (!alias) VMC(4); else VMC(2);      // x drained; wt+pubs fly
            } else {
                MPOLL(t + 1);                         // wave1 gate (producer mflags)
                VMC(0);                               // drain own Hd(+Out/wt) acks
                RAWBAR();                             // gate barrier (covers all waves)
                STAGE_X(t + 1);                       // 16 gld16
                if (l == 1 && !alias) {
                    st_wt16(Xw + i0, hb0); st_wt16(Xw + i1, hb1);
                    st_wt16(Xw + i2, hb2); st_wt16(Xw + i3, hb3);
                }
                MEMBAR(); SBAR();
                if (lane == 0) {
                    st_plain32(myIf, (unsigned)(t + 1));
                    st_wt32(myMf, (unsigned)(t + 1));
                }
                MEMBAR(); SBAR();
                if (l == 1 && !alias) VMC(6); else VMC(2);   // x drained
            }
            RAWBAR();                                 // B3: x(t+1) staged
            e0 = (f32x4){0,0,0,0}; e1 = (f32x4){0,0,0,0};
            o0 = (f32x4){0,0,0,0}; o1 = (f32x4){0,0,0,0};
            { XH(e0, e1, o0, o1, A00, A01) }
            if (P == 2) {
                e2 = (f32x4){0,0,0,0}; e3 = (f32x4){0,0,0,0};
                o2 = (f32x4){0,0,0,0}; o3 = (f32x4){0,0,0,0};
                XH(e2, e3, o2, o3, A10, A11)
            }
        } else {
            // final-step tail: last Xq copy (shadow skipped)
            if (!alias && l == 0) { st_wt16(Xw + i0, hb0); st_wt16(Xw + i1, hb1); }
            if (!alias && l == 1) { st_wt16(Xw + i0, hb0); st_wt16(Xw + i1, hb1);
                                    st_wt16(Xw + i2, hb2); st_wt16(Xw + i3, hb3); }
            MEMBAR(); SBAR();
            VMC(0);
            RAWBAR();
        }
    }

    // ---- epilogue: publish T per wave (after full drain -> clamp gate safe)
    VMC(0);
    __builtin_amdgcn_s_barrier();
    if (lane == 0) {
        st_plain32(myIf, (unsigned)T);
        st_wt32(myMf, (unsigned)T);
    }
}

extern "C" void kernel_launch(void* const* d_in, const int* in_sizes, int n_in,
                              void* d_out, int out_size, void* d_ws, size_t ws_size,
                              hipStream_t stream)
{
    const float* x = (const float*)d_in[0];
    const float* Wih[3] = {(const float*)d_in[1], (const float*)d_in[5], (const float*)d_in[9]};
    const float* Whh[3] = {(const float*)d_in[2], (const float*)d_in[6], (const float*)d_in[10]};
    const float* bih[3] = {(const float*)d_in[3], (const float*)d_in[7], (const float*)d_in[11]};
    const float* bhh[3] = {(const float*)d_in[4], (const float*)d_in[8], (const float*)d_in[12]};

    char* wp = (char*)d_ws;
    const size_t SZ_A = (size_t)16384 * 512;
    unsigned int* flags = (unsigned int*)wp; wp += 65536;   // 2 * 8*32 lines * 128B
    unsigned short* Xp  = (unsigned short*)wp; wp += SZ_A * 2;
    unsigned short* Hp0 = (unsigned short*)wp; wp += SZ_A * 2;
    unsigned short* Hp1 = (unsigned short*)wp; wp += SZ_A * 2;
    unsigned short* Hp2 = (unsigned short*)wp; wp += SZ_A * 2;
    unsigned short* Wp[3];
    for (int l = 0; l < 3; ++l) { Wp[l] = (unsigned short*)wp; wp += (size_t)2048 * 1024 * 2; }
    unsigned short* Xq1 = (unsigned short*)wp; wp += SZ_A * 2;
    unsigned short* Xq2 = (unsigned short*)wp; wp += SZ_A * 2;
    const size_t need = (size_t)(wp - (char*)d_ws);
    if (ws_size < need) { Xq1 = Hp0; Xq2 = Hp1; }   // fallback: sc1-only h path

    hipMemsetAsync(flags, 0, 65536, stream);
    k_conv_x<<<dim3(4096), dim3(256), 0, stream>>>(x, Xp);
    for (int l = 0; l < 3; ++l)
        k_conv_w<<<dim3(1024), dim3(256), 0, stream>>>(Wih[l], Whh[l], Wp[l]);

    DP dp;
    dp.Xp = Xp; dp.Hp0 = Hp0; dp.Hp1 = Hp1; dp.Hp2 = Hp2;
    dp.Xq1 = Xq1; dp.Xq2 = Xq2;
    dp.Wp0 = Wp[0]; dp.Wp1 = Wp[1]; dp.Wp2 = Wp[2];
    dp.bi0 = bih[0]; dp.bh0 = bhh[0];
    dp.bi1 = bih[1]; dp.bh1 = bhh[1];
    dp.bi2 = bih[2]; dp.bh2 = bhh[2];
    dp.Out = (float*)d_out; dp.flags = flags;

    k_drnn<<<dim3(256), dim3(256), 0, stream>>>(dp);
}

// Round 19
// 894.128 us; speedup vs baseline: 1.2028x; 1.2028x over previous
//
#include <hip/hip_runtime.h>

typedef __attribute__((ext_vector_type(8))) short bf16x8;
typedef __attribute__((ext_vector_type(4))) float f32x4;

__device__ __forceinline__ unsigned short f2bf(float x) {
    unsigned u = __float_as_uint(x);
    u += 0x7FFFu + ((u >> 16) & 1u);
    return (unsigned short)(u >> 16);
}
__device__ __forceinline__ float sigm(float x) { return 1.0f / (1.0f + __expf(-x)); }
__device__ __forceinline__ float ftanh(float x) {
    float e = __expf(2.f * x);
    return 1.f - 2.f / (e + 1.f);
}

// async global->LDS, 16B/lane, wave-uniform LDS base + lane*16
__device__ __forceinline__ void gld16(const unsigned short* g, unsigned short* l) {
    __builtin_amdgcn_global_load_lds((const __attribute__((address_space(1))) void*)g,
                                     (__attribute__((address_space(3))) void*)l, 16, 0, 0);
}

// ---- flag primitives ----
__device__ __forceinline__ void st_plain32(unsigned* p, unsigned v) {  // -> XCD L2 (write-through)
    asm volatile("global_store_dword %0, %1, off" :: "v"(p), "v"(v) : "memory");
}
__device__ __forceinline__ void st_wt32(unsigned* p, unsigned v) {     // -> MALL
    asm volatile("global_store_dword %0, %1, off sc0 sc1" :: "v"(p), "v"(v) : "memory");
}
__device__ __forceinline__ void aaddMALL(unsigned* p) {
    unsigned one = 1;
    asm volatile("global_atomic_add %0, %1, off sc1" :: "v"(p), "v"(one) : "memory");
}
__device__ __forceinline__ unsigned ld_mall(const unsigned* p) {       // read MALL
    unsigned v;
    asm volatile("global_load_dword %0, %1, off sc0 sc1\n\ts_waitcnt vmcnt(0)"
                 : "=v"(v) : "v"(p) : "memory");
    return v;
}
__device__ __forceinline__ void st_wt16(unsigned short* p, unsigned v) {
    asm volatile("global_store_short %0, %1, off sc0 sc1" :: "v"(p), "v"(v) : "memory");
}

// DPP quad-lane exchanges (1-cycle VALU)
__device__ __forceinline__ float dppx1(float x) {
    return __int_as_float(__builtin_amdgcn_mov_dpp(__float_as_int(x), 0xB1, 0xF, 0xF, true));
}
__device__ __forceinline__ float dppx2(float x) {
    return __int_as_float(__builtin_amdgcn_mov_dpp(__float_as_int(x), 0x4E, 0xF, 0xF, true));
}

// ---------------- packing kernels (round-6-verified) ----------------
__global__ __launch_bounds__(256) void k_conv_x(const float* __restrict__ x,
                                                unsigned short* __restrict__ Xp) {
    int i = blockIdx.x * 256 + threadIdx.x;
    int rb = i >> 10, kc = (i >> 6) & 15, ln = i & 63;
    int row = (rb << 4) + (ln & 15);
    int k   = (kc << 5) + ((ln >> 4) << 3);
    const float* s = x + (size_t)row * 512 + k;
    float4 v0 = *(const float4*)s, v1 = *(const float4*)(s + 4);
    unsigned short o[8] = {f2bf(v0.x), f2bf(v0.y), f2bf(v0.z), f2bf(v0.w),
                           f2bf(v1.x), f2bf(v1.y), f2bf(v1.z), f2bf(v1.w)};
    *(bf16x8*)(Xp + (size_t)i * 8) = *(bf16x8*)o;
}

__global__ __launch_bounds__(256) void k_conv_w(const float* __restrict__ Wih,
                                                const float* __restrict__ Whh,
                                                unsigned short* __restrict__ Wp) {
    int i = blockIdx.x * 256 + threadIdx.x;
    int wrb = i >> 11, kc = (i >> 6) & 31, ln = i & 63;
    int j = (wrb << 4) + (ln & 15);
    int k = (kc << 5) + ((ln >> 4) << 3);
    int srow = (j & 3) * 512 + (j >> 2);              // torch row g*512+hc
    const float* s = (k < 512) ? (Wih + (size_t)srow * 512 + k)
                               : (Whh + (size_t)srow * 512 + (k - 512));
    float4 v0 = *(const float4*)s, v1 = *(const float4*)(s + 4);
    unsigned short o[8] = {f2bf(v0.x), f2bf(v0.y), f2bf(v0.z), f2bf(v0.w),
                           f2bf(v1.x), f2bf(v1.y), f2bf(v1.z), f2bf(v1.w)};
    *(bf16x8*)(Wp + (size_t)i * 8) = *(bf16x8*)o;
}

struct DP {
    const unsigned short* Xp;
    unsigned short *Hp0, *Hp1, *Hp2;
    unsigned short *Xq1, *Xq2;
    const unsigned short *Wp0, *Wp1, *Wp2;
    const float *bi0, *bh0, *bi1, *bh1, *bi2, *bh2;
    float* Out;
    unsigned int* flags;   // [0,256) iflagV, [256,512) mflagV, [512,768) cflagS
};

__device__ __forceinline__ void quadT(f32x4 a, int sq, float& G0, float& G1, float& G2, float& G3) {
    float a0 = a[0], a1 = a[1], a2 = a[2], a3 = a[3];
    float p1 = (sq & 1) ? a0 : a1; float g1_ = dppx1(p1);
    float p2 = (sq & 1) ? a2 : a3; float g2_ = dppx1(p2);
    float m0 = (sq & 1) ? g1_ : a0, m1 = (sq & 1) ? a1 : g1_;
    float m2 = (sq & 1) ? g2_ : a2, m3 = (sq & 1) ? a3 : g2_;
    float q1 = (sq & 2) ? m0 : m2; float h1_ = dppx2(q1);
    float q2 = (sq & 2) ? m1 : m3; float h2_ = dppx2(q2);
    G0 = (sq & 2) ? h1_ : m0; G1 = (sq & 2) ? h2_ : m1;
    G2 = (sq & 2) ? m2 : h1_; G3 = (sq & 2) ? m3 : h2_;
}

#define PIN8(A,B,C,D,E,F,G,H) \
    asm volatile("" : "+v"(A),"+v"(B),"+v"(C),"+v"(D),"+v"(E),"+v"(F),"+v"(G),"+v"(H))
#define SBAR()  __builtin_amdgcn_sched_barrier(0)
#define MEMBAR() asm volatile("" ::: "memory")
#define RAWBAR() do { MEMBAR(); SBAR(); __builtin_amdgcn_s_barrier(); SBAR(); MEMBAR(); } while (0)
#define VMC(n) asm volatile("s_waitcnt vmcnt(" #n ")" ::: "memory")

// Persistent dilated-LSTM, grid 256, XCD-clustered (cid = bid&7, w = bid>>3).
// r16-best configuration (883us, reverted after r17/r18 experiments showed
// null/regression): issue-order-aware counted vmcnt so MALL-bound stores
// (st_wt16 Xq copies, pubs) are issued NEWEST in each wave's queue; shared
// 128B flag line per cluster; block-wide publish after B2.
// Per-step order (l==0): Hd plain stores -> STAGE_X gld16 -> wt16 ->
// vmcnt(10) [drains Hd only, overlapped with gld16 flight] -> B2 ->
// pubs(w3) -> w3 vmcnt(5|4) / others vmcnt(2) [wt16+pubs stay flying;
// retire during XH+poll] -> B3 -> XH. Last step issues wt16 in the tail.
// l==1 same behind the CPOLL gate; l==2 leaves the 4 Out stores flying.
// t==0: guard RAWBAR before l==0's first x-overwrite (prologue XH).
// Flags: plain-store iflag publish + gld16 poll (exact-match (v-t)<=1;
// t==T-1 via MALL mirror; 1024-iter permanent escalation); cflag = MALL
// sums, one step delayed, totals 32*T.
__global__ __launch_bounds__(256, 1) void k_drnn(DP p) {
    const int tid = threadIdx.x, lane = tid & 63, wv = tid >> 6;
    const int l15 = lane & 15, lhi = lane >> 4, sq = l15 & 3;

    const int b = blockIdx.x;
    const int cid = b & 7, w = b >> 3;
    int l, c, T, P, N;
    if (cid < 2)      { l = 0; c = cid;     T = 256; P = 1; N = 64;  }
    else if (cid < 4) { l = 1; c = cid - 2; T = 128; P = 2; N = 128; }
    else              { l = 2; c = cid - 4; T = 64;  P = 2; N = 256; }

    const unsigned short* Xs = (l == 0) ? p.Xp  : (l == 1 ? p.Xq1 : p.Xq2);
    unsigned short*       Hd = (l == 0) ? p.Hp0 : (l == 1 ? p.Hp1 : p.Hp2);
    unsigned short*       Xw = (l == 0) ? p.Xq1 : (l == 1 ? p.Xq2 : nullptr);
    const unsigned short* Ws = (l == 0) ? p.Wp0 : (l == 1 ? p.Wp1 : p.Wp2);
    const float* bi = (l == 0) ? p.bi0 : (l == 1 ? p.bi1 : p.bi2);
    const float* bh = (l == 0) ? p.bh0 : (l == 1 ? p.bh1 : p.bh2);
    const int R0 = c * (P * 32);
    const int alias = (p.Xq1 == p.Hp0);

    __shared__ unsigned short At[65536];   // 128 KiB
    __shared__ unsigned pollbuf[32];       // flag-line scratch

    const unsigned short* wbase = Ws + ((size_t)(((w << 2) + wv) * 32) << 9) + lane * 8;
#define DECLW(n) bf16x8 w##n = *(const bf16x8*)(wbase + (n << 9));
    DECLW(0) DECLW(1) DECLW(2) DECLW(3) DECLW(4) DECLW(5) DECLW(6) DECLW(7)
    DECLW(8) DECLW(9) DECLW(10) DECLW(11) DECLW(12) DECLW(13) DECLW(14) DECLW(15)
    DECLW(16) DECLW(17) DECLW(18) DECLW(19) DECLW(20) DECLW(21) DECLW(22) DECLW(23)
    DECLW(24) DECLW(25) DECLW(26) DECLW(27) DECLW(28) DECLW(29) DECLW(30) DECLW(31)

    const int hcol = (w << 4) + (wv << 2) + (l15 >> 2);
    const float bs0 = bi[hcol]        + bh[hcol];
    const float bs1 = bi[512 + hcol]  + bh[512 + hcol];
    const float bs2 = bi[1024 + hcol] + bh[1024 + hcol];
    const float bs3 = bi[1536 + hcol] + bh[1536 + hcol];

    const int kch = hcol >> 5;
    const int lane16 = (((hcol & 31) >> 3) << 4) + ((lhi << 2) + sq);
    const int st_lt = lane16 * 8 + (hcol & 7);

    float cst0 = 0.f, cst1 = 0.f, cst2 = 0.f, cst3 = 0.f;
    unsigned int* iflagV = p.flags;
    unsigned int* mflagV = p.flags + 256;
    unsigned int* cflagS = p.flags + 512;
    int fastok = 1;

#define KPX(na, nb, E0, E1, O0, O1, A0, A1) { \
    bf16x8 xa = *(const bf16x8*)((A0) + ((na) << 9)); \
    bf16x8 xb = *(const bf16x8*)((A1) + ((na) << 9)); \
    bf16x8 ya = *(const bf16x8*)((A0) + ((nb) << 9)); \
    bf16x8 yb = *(const bf16x8*)((A1) + ((nb) << 9)); \
    E0 = __builtin_amdgcn_mfma_f32_16x16x32_bf16(xa, w##na, E0, 0, 0, 0); \
    E1 = __builtin_amdgcn_mfma_f32_16x16x32_bf16(xb, w##na, E1, 0, 0, 0); \
    O0 = __builtin_amdgcn_mfma_f32_16x16x32_bf16(ya, w##nb, O0, 0, 0, 0); \
    O1 = __builtin_amdgcn_mfma_f32_16x16x32_bf16(yb, w##nb, O1, 0, 0, 0); }

#define XH(E0, E1, O0, O1, A0, A1) \
    KPX(0,1,E0,E1,O0,O1,A0,A1) KPX(2,3,E0,E1,O0,O1,A0,A1) \
    KPX(4,5,E0,E1,O0,O1,A0,A1) KPX(6,7,E0,E1,O0,O1,A0,A1) \
    KPX(8,9,E0,E1,O0,O1,A0,A1) KPX(10,11,E0,E1,O0,O1,A0,A1) \
    KPX(12,13,E0,E1,O0,O1,A0,A1) KPX(14,15,E0,E1,O0,O1,A0,A1)
#define HH(E0, E1, O0, O1, A0, A1) \
    KPX(16,17,E0,E1,O0,O1,A0,A1) KPX(18,19,E0,E1,O0,O1,A0,A1) \
    KPX(20,21,E0,E1,O0,O1,A0,A1) KPX(22,23,E0,E1,O0,O1,A0,A1) \
    KPX(24,25,E0,E1,O0,O1,A0,A1) KPX(26,27,E0,E1,O0,O1,A0,A1) \
    KPX(28,29,E0,E1,O0,O1,A0,A1) KPX(30,31,E0,E1,O0,O1,A0,A1)

#define PWC(RV, CSTV, HV) { \
    float G0, G1, G2, G3; quadT(RV, sq, G0, G1, G2, G3); \
    float cn = sigm(G1 + bs1) * CSTV + sigm(G0 + bs0) * ftanh(G2 + bs2); \
    HV = sigm(G3 + bs3) * ftanh(cn); CSTV = cn; }

#define STAGE_X(TT) { \
    const int RxN = ((TT) * N + R0) >> 4; \
    for (int i = 0; i < P * 8; ++i) { \
        int q = wv * (P * 8) + i, rb = q >> 4, kc = q & 15; \
        gld16(Xs + ((size_t)((RxN + rb) * 16 + kc) << 9) + lane * 8, \
              &At[(rb * 32 + kc) << 9]); } }
#define STAGE_H(TT) { \
    const int RhN = ((TT) * N + R0) >> 4; \
    for (int i = 0; i < P * 8; ++i) { \
        int q = wv * (P * 8) + i, rb = q >> 4, kc = q & 15; \
        gld16(Hd + ((size_t)((RhN + rb) * 16 + kc) << 9) + lane * 8, \
              &At[(rb * 32 + 16 + kc) << 9]); } }

#define CPOLL(TT) { \
    if (l == 1 && wv == 1 && lane < 2) { \
        const unsigned* cp = cflagS + lane * 32; \
        const unsigned need = 32u * (unsigned)(2 * (TT) + c + 1); \
        int n = 0; \
        while (!__all(ld_mall(cp) >= need)) { if (++n > (1 << 22)) break; } \
    } \
    if (l == 2 && wv == 1 && lane == 0) { \
        const unsigned* cp = cflagS + (2 + (c & 1)) * 32; \
        const unsigned need = 32u * (unsigned)(2 * (TT) + (c >> 1) + 1); \
        int n = 0; \
        while (ld_mall(cp) < need) { if (++n > (1 << 22)) break; } \
    } }

    f32x4 e0 = {0,0,0,0}, e1 = {0,0,0,0}, o0 = {0,0,0,0}, o1 = {0,0,0,0};
    f32x4 e2 = {0,0,0,0}, e3 = {0,0,0,0}, o2 = {0,0,0,0}, o3 = {0,0,0,0};
    const unsigned short* A00 = At + lane * 8;
    const unsigned short* A01 = A00 + (32 << 9);
    const unsigned short* A10 = A00 + (64 << 9);
    const unsigned short* A11 = A00 + (96 << 9);

    // ---------- prologue: x(0) staged + x-half partials ----------
    CPOLL(0);
    RAWBAR();
    STAGE_X(0);
    VMC(0);
    RAWBAR();
    { XH(e0, e1, o0, o1, A00, A01) }
    if (P == 2) { XH(e2, e3, o2, o3, A10, A11) }

    for (int t = 0; t < T; ++t) {
        PIN8(w0,w1,w2,w3,w4,w5,w6,w7);
        PIN8(w8,w9,w10,w11,w12,w13,w14,w15);
        PIN8(w16,w17,w18,w19,w20,w21,w22,w23);
        PIN8(w24,w25,w26,w27,w28,w29,w30,w31);

        const int RxB = (t * N + R0) >> 4;

        if (t > 0) {
            if (wv == 0) {
                const unsigned need = (unsigned)t;
                const unsigned* mp = mflagV + cid * 32 + (lane & 31);
                if (t == T - 1 || !fastok) {         // authoritative MALL gate
                    int n = 0;
                    while (!__all(ld_mall(mp) >= need)) { if (++n > (1 << 22)) break; }
                } else {
                    const unsigned short* gip = (const unsigned short*)(iflagV + cid * 32);
                    volatile unsigned* pb = pollbuf;
                    int n = 0;
                    for (;;) {
                        if (lane < 8) gld16(gip + lane * 8, (unsigned short*)pollbuf);
                        VMC(0);
                        SBAR();
                        unsigned v = pb[lane & 31];
                        if (__all((v - need) <= 1u)) break;
                        if (++n > 1024) {
                            fastok = 0;
                            int m = 0;
                            while (!__all(ld_mall(mp) >= need)) { if (++m > (1 << 22)) break; }
                            break;
                        }
                    }
                }
            }
            RAWBAR();                                 // B0: h(t-1) ready
            STAGE_H(t - 1);
            VMC(0);
            RAWBAR();                                 // B1: h staged
            { HH(e0, e1, o0, o1, A00, A01) }
            if (P == 2) { HH(e2, e3, o2, o3, A10, A11) }
        }

        // ---- pointwise
        float hv0, hv1, hv2 = 0.f, hv3 = 0.f;
        { f32x4 r0 = e0 + o0, r1 = e1 + o1;
          PWC(r0, cst0, hv0) PWC(r1, cst1, hv1) }
        if (P == 2) {
          f32x4 r2 = e2 + o2, r3 = e3 + o3;
          PWC(r2, cst2, hv2) PWC(r3, cst3, hv3) }

        const unsigned short hb0 = f2bf(hv0), hb1 = f2bf(hv1);
        const unsigned short hb2 = f2bf(hv2), hb3 = f2bf(hv3);
        const size_t i0 = ((size_t)((RxB + 0) * 16 + kch) << 9) + st_lt;
        const size_t i1 = ((size_t)((RxB + 1) * 16 + kch) << 9) + st_lt;
        const size_t i2 = ((size_t)((RxB + 2) * 16 + kch) << 9) + st_lt;
        const size_t i3 = ((size_t)((RxB + 3) * 16 + kch) << 9) + st_lt;

        // ---- release stores (plain; MALL wt16 deferred to the shadow)
        if (!alias || l == 2) {
            Hd[i0] = hb0; Hd[i1] = hb1;
            if (P == 2) { Hd[i2] = hb2; Hd[i3] = hb3; }
        }
        if (alias && l < 2) {                        // fallback: wt IS the h store
            st_wt16(Xw + i0, hb0); st_wt16(Xw + i1, hb1);
            if (P == 2) { st_wt16(Xw + i2, hb2); st_wt16(Xw + i3, hb3); }
        }
        if (l == 2) {
            p.Out[((size_t)(((RxB + 0) << 4) + (lhi << 2) + sq)) * 512 + hcol] = hv0;
            p.Out[((size_t)(((RxB + 1) << 4) + (lhi << 2) + sq)) * 512 + hcol] = hv1;
            p.Out[((size_t)(((RxB + 2) << 4) + (lhi << 2) + sq)) * 512 + hcol] = hv2;
            p.Out[((size_t)(((RxB + 3) << 4) + (lhi << 2) + sq)) * 512 + hcol] = hv3;
        }
        MEMBAR(); SBAR();

        if (t + 1 < T) {
            if (l == 0) {
                if (t == 0) RAWBAR();                 // guard: prologue-XH vs x overwrite
                STAGE_X(t + 1);                       // 8 gld16
                if (!alias) { st_wt16(Xw + i0, hb0); st_wt16(Xw + i1, hb1); }
                MEMBAR(); SBAR();
                if (!alias) VMC(10);                  // drain 2 Hd; 8g+2wt fly
                else        VMC(8);                   // drain 2 wt16 (h); 8g fly
                RAWBAR();                             // B2
                if (tid == 192) {
                    st_plain32(iflagV + cid * 32 + w, (unsigned)(t + 1));
                    st_wt32(mflagV + cid * 32 + w, (unsigned)(t + 1));
                    if (t > 0) aaddMALL(cflagS + cid * 32);
                }
                MEMBAR(); SBAR();
                if (!alias) {
                    if (wv == 3) { if (t > 0) VMC(5); else VMC(4); } else VMC(2);
                } else {
                    if (wv == 3) { if (t > 0) VMC(3); else VMC(2); } else VMC(0);
                }
            } else {
                CPOLL(t + 1);                         // wave1 gate (producer data)
                if (l == 2) VMC(4); else VMC(0);      // drain Hd (l2: leave Out)
                RAWBAR();                             // B2 (gate + h drained)
                STAGE_X(t + 1);                       // 16 gld16
                if (l == 1 && !alias) {
                    st_wt16(Xw + i0, hb0); st_wt16(Xw + i1, hb1);
                    st_wt16(Xw + i2, hb2); st_wt16(Xw + i3, hb3);
                }
                MEMBAR(); SBAR();
                if (tid == 192) {
                    st_plain32(iflagV + cid * 32 + w, (unsigned)(t + 1));
                    st_wt32(mflagV + cid * 32 + w, (unsigned)(t + 1));
                    if (l == 1 && t > 0) aaddMALL(cflagS + cid * 32);
                }
                MEMBAR(); SBAR();
                if (l == 1) {
                    if (!alias) { if (wv == 3) { if (t > 0) VMC(7); else VMC(6); } else VMC(4); }
                    else        { if (wv == 3) { if (t > 0) VMC(3); else VMC(2); } else VMC(0); }
                } else {
                    if (wv == 3) VMC(2); else VMC(0);
                }
            }
            RAWBAR();                                 // B3: x(t+1) staged
            e0 = (f32x4){0,0,0,0}; e1 = (f32x4){0,0,0,0};
            o0 = (f32x4){0,0,0,0}; o1 = (f32x4){0,0,0,0};
            { XH(e0, e1, o0, o1, A00, A01) }
            if (P == 2) {
                e2 = (f32x4){0,0,0,0}; e3 = (f32x4){0,0,0,0};
                o2 = (f32x4){0,0,0,0}; o3 = (f32x4){0,0,0,0};
                XH(e2, e3, o2, o3, A10, A11)
            }
        } else {
            // final-step tail: last Xq copy (shadow skipped)
            if (!alias && l == 0) { st_wt16(Xw + i0, hb0); st_wt16(Xw + i1, hb1); }
            if (!alias && l == 1) { st_wt16(Xw + i0, hb0); st_wt16(Xw + i1, hb1);
                                    st_wt16(Xw + i2, hb2); st_wt16(Xw + i3, hb3); }
            MEMBAR(); SBAR();
            VMC(0);
            RAWBAR();
        }
    }

    // ---- epilogue: final publishes (stale-reject margin + exact sums 32*T)
    VMC(0);
    __builtin_amdgcn_s_barrier();
    if (tid == 192) {
        st_plain32(iflagV + cid * 32 + w, (unsigned)T);
        st_wt32(mflagV + cid * 32 + w, (unsigned)T);
        if (l < 2) { aaddMALL(cflagS + cid * 32); aaddMALL(cflagS + cid * 32); }
    }
}

extern "C" void kernel_launch(void* const* d_in, const int* in_sizes, int n_in,
                              void* d_out, int out_size, void* d_ws, size_t ws_size,
                              hipStream_t stream)
{
    const float* x = (const float*)d_in[0];
    const float* Wih[3] = {(const float*)d_in[1], (const float*)d_in[5], (const float*)d_in[9]};
    const float* Whh[3] = {(const float*)d_in[2], (const float*)d_in[6], (const float*)d_in[10]};
    const float* bih[3] = {(const float*)d_in[3], (const float*)d_in[7], (const float*)d_in[11]};
    const float* bhh[3] = {(const float*)d_in[4], (const float*)d_in[8], (const float*)d_in[12]};

    char* wp = (char*)d_ws;
    const size_t SZ_A = (size_t)16384 * 512;
    unsigned int* flags = (unsigned int*)wp; wp += 4096;
    unsigned short* Xp  = (unsigned short*)wp; wp += SZ_A * 2;
    unsigned short* Hp0 = (unsigned short*)wp; wp += SZ_A * 2;
    unsigned short* Hp1 = (unsigned short*)wp; wp += SZ_A * 2;
    unsigned short* Hp2 = (unsigned short*)wp; wp += SZ_A * 2;
    unsigned short* Wp[3];
    for (int l = 0; l < 3; ++l) { Wp[l] = (unsigned short*)wp; wp += (size_t)2048 * 1024 * 2; }
    unsigned short* Xq1 = (unsigned short*)wp; wp += SZ_A * 2;
    unsigned short* Xq2 = (unsigned short*)wp; wp += SZ_A * 2;
    const size_t need = (size_t)(wp - (char*)d_ws);
    if (ws_size < need) { Xq1 = Hp0; Xq2 = Hp1; }   // fallback: sc1-only h path

    hipMemsetAsync(flags, 0, 4096, stream);
    k_conv_x<<<dim3(4096), dim3(256), 0, stream>>>(x, Xp);
    for (int l = 0; l < 3; ++l)
        k_conv_w<<<dim3(1024), dim3(256), 0, stream>>>(Wih[l], Whh[l], Wp[l]);

    DP dp;
    dp.Xp = Xp; dp.Hp0 = Hp0; dp.Hp1 = Hp1; dp.Hp2 = Hp2;
    dp.Xq1 = Xq1; dp.Xq2 = Xq2;
    dp.Wp0 = Wp[0]; dp.Wp1 = Wp[1]; dp.Wp2 = Wp[2];
    dp.bi0 = bih[0]; dp.bh0 = bhh[0];
    dp.bi1 = bih[1]; dp.bh1 = bhh[1];
    dp.bi2 = bih[2]; dp.bh2 = bhh[2];
    dp.Out = (float*)d_out; dp.flags = flags;

    k_drnn<<<dim3(256), dim3(256), 0, stream>>>(dp);
}